// Round 3
// baseline (174.488 us; speedup 1.0000x reference)
//
#include <hip/hip_runtime.h>

#define CH      256
#define HH      128
#define WW      128
#define HWPIX   (HH * WW)       // 16384
#define TILE_PX 256             // pixels per block (2 full rows)
#define QUADS   64              // float4 pixel-quads per tile
#define CGROUPS 16              // channel groups
#define CPG     16              // channels per group
#define NTHR    1024            // QUADS * CGROUPS

// Single pass, register-resident: each wave-load is 1 KB contiguous
// (64 lanes x float4 at uniform channel-group). x is read from HBM once,
// out written once.
__global__ __launch_bounds__(NTHR) void k_fused(
    const float* __restrict__ x,
    const float* __restrict__ bboxes,
    const int*   __restrict__ batch_idx,
    float*       __restrict__ out,
    int N)
{
    const int tilesPerImg = HWPIX / TILE_PX;        // 64
    const int b    = blockIdx.x / tilesPerImg;
    const int tile = blockIdx.x % tilesPerImg;
    const int pix0 = tile * TILE_PX;

    const int q = threadIdx.x & (QUADS - 1);        // 0..63, uniform stride in a wave
    const int g = threadIdx.x >> 6;                 // 0..15, uniform per wave

    const int pixq = pix0 + 4 * q;                  // first pixel of quad
    const size_t base = ((size_t)b * CH + (size_t)g * CPG) * HWPIX + pixq;
    const float4* __restrict__ xq = (const float4*)(x + base);

    // ---- issue 16 independent 1KB-per-wave loads ----
    float4 v[CPG];
    #pragma unroll
    for (int j = 0; j < CPG; ++j)
        v[j] = xq[(size_t)j * (HWPIX / 4)];

    // ---- rasterize boxes while loads are in flight (uniform scalar work) ----
    const int h  = pixq >> 7;
    const int w0 = pixq & (WW - 1);
    int in0 = 0, in1 = 0, in2 = 0, in3 = 0;
    for (int n = 0; n < N; ++n) {
        if (batch_idx[n] != b) continue;
        const float xc = bboxes[4 * n + 0];
        const float yc = bboxes[4 * n + 1];
        const float bw = bboxes[4 * n + 2];
        const float bh = bboxes[4 * n + 3];
        // match jnp.trunc(...).astype(int32) then max/min clamps exactly
        const int x1 = max(0,      (int)truncf((xc - bw * 0.5f) * (float)WW));
        const int y1 = max(0,      (int)truncf((yc - bh * 0.5f) * (float)HH));
        const int x2 = min(WW - 1, (int)truncf((xc + bw * 0.5f) * (float)WW));
        const int y2 = min(HH - 1, (int)truncf((yc + bh * 0.5f) * (float)HH));
        if (!(x2 > x1 && y2 > y1)) continue;
        if (h < y1 || h > y2) continue;
        in0 |= (w0 + 0 >= x1) & (w0 + 0 <= x2);
        in1 |= (w0 + 1 >= x1) & (w0 + 1 <= x2);
        in2 |= (w0 + 2 >= x1) & (w0 + 2 <= x2);
        in3 |= (w0 + 3 >= x1) & (w0 + 3 <= x2);
    }

    // ---- per-thread partial sum over its 16 channels ----
    float4 ps = make_float4(0.f, 0.f, 0.f, 0.f);
    #pragma unroll
    for (int j = 0; j < CPG; ++j) {
        ps.x += v[j].x; ps.y += v[j].y; ps.z += v[j].z; ps.w += v[j].w;
    }

    // ---- cross-group reduce via LDS (16 KB) ----
    __shared__ float4 part[CGROUPS][QUADS];
    part[g][q] = ps;
    __syncthreads();

    float4 tot = make_float4(0.f, 0.f, 0.f, 0.f);
    #pragma unroll
    for (int gg = 0; gg < CGROUPS; ++gg) {
        const float4 p = part[gg][q];
        tot.x += p.x; tot.y += p.y; tot.z += p.z; tot.w += p.w;
    }

    const float inv = 1.0f / (float)CH;
    float4 a;
    a.x = in0 ? tot.x * inv : 0.0f;
    a.y = in1 ? tot.y * inv : 0.0f;
    a.z = in2 ? tot.z * inv : 0.0f;
    a.w = in3 ? tot.w * inv : 0.0f;

    // ---- write out = x + addend from registers (1 KB contiguous stores) ----
    float4* __restrict__ oq = (float4*)(out + base);
    #pragma unroll
    for (int j = 0; j < CPG; ++j) {
        float4 o = v[j];
        o.x += a.x; o.y += a.y; o.z += a.z; o.w += a.w;
        oq[(size_t)j * (HWPIX / 4)] = o;
    }
}

extern "C" void kernel_launch(void* const* d_in, const int* in_sizes, int n_in,
                              void* d_out, int out_size, void* d_ws, size_t ws_size,
                              hipStream_t stream)
{
    const float* x         = (const float*)d_in[0];
    const float* bboxes    = (const float*)d_in[1];
    const int*   batch_idx = (const int*)d_in[2];
    float*       out       = (float*)d_out;

    const int N = in_sizes[1] / 4;                  // 320 boxes
    const int B = 16;

    const int blocks = B * (HWPIX / TILE_PX);       // 1024
    k_fused<<<blocks, NTHR, 0, stream>>>(x, bboxes, batch_idx, out, N);
}

// Round 4
// 110.465 us; speedup vs baseline: 1.5796x; 1.5796x over previous
//
#include <hip/hip_runtime.h>

#define CH      256
#define HH      128
#define WW      128
#define HWPIX   (HH * WW)       // 16384
#define TILE_PX 64              // pixels per block = half a row (one u64 mask word)
#define QUADS   16              // float4 pixel-quads per tile
#define CGROUPS 16              // channel groups
#define CPG     16              // channels per group
#define NTHR    256

// Single pass, register-resident. Box rasterization is done ONCE per block
// into a 64-bit row mask (the 64-px tile lives in one row, one u64 word),
// so the per-pixel cost is a bit test instead of a 320-iteration loop.
__global__ __launch_bounds__(NTHR, 4) void k_fused(
    const float*  __restrict__ x,
    const float4* __restrict__ bb4,     // bboxes as [N] float4
    const int*    __restrict__ batch_idx,
    float*        __restrict__ out,
    int N)
{
    const int b    = blockIdx.x >> 8;          // 256 tiles per image
    const int tile = blockIdx.x & 255;
    const int pix0 = tile * TILE_PX;
    const int h     = tile >> 1;               // row of this tile
    const int wbase = (tile & 1) << 6;         // 0 or 64: which u64 word

    const int q = threadIdx.x & (QUADS - 1);   // 0..15 pixel-quad
    const int g = threadIdx.x >> 4;            // 0..15 channel group

    const int pixq = pix0 + 4 * q;
    const size_t base = ((size_t)b * CH + (size_t)g * CPG) * HWPIX + pixq;
    const float4* __restrict__ xq = (const float4*)(x + base);

    // ---- issue all 16 independent loads; keep them live in VGPRs ----
    float4 v[CPG];
    #pragma unroll
    for (int j = 0; j < CPG; ++j)
        v[j] = xq[(size_t)j * (HWPIX / 4)];

    // ---- cooperative rasterization into one u64 row-mask ----
    __shared__ unsigned long long smask;
    if (threadIdx.x == 0) smask = 0ull;
    __syncthreads();

    for (int n = threadIdx.x; n < N; n += NTHR) {
        if (batch_idx[n] != b) continue;
        const float4 bx = bb4[n];
        // match jnp.trunc(...).astype(int32) then max/min clamps exactly
        const int x1 = max(0,      (int)truncf((bx.x - bx.z * 0.5f) * (float)WW));
        const int y1 = max(0,      (int)truncf((bx.y - bx.w * 0.5f) * (float)HH));
        const int x2 = min(WW - 1, (int)truncf((bx.x + bx.z * 0.5f) * (float)WW));
        const int y2 = min(HH - 1, (int)truncf((bx.y + bx.w * 0.5f) * (float)HH));
        if (!(x2 > x1 && y2 > y1)) continue;
        if (h < y1 || h > y2) continue;
        const int a0 = max(x1 - wbase, 0);
        const int b0 = min(x2 - wbase, 63);
        if (a0 > b0) continue;
        const unsigned long long hi = (b0 == 63) ? ~0ull : ((1ull << (b0 + 1)) - 1ull);
        const unsigned long long lo = (1ull << a0) - 1ull;
        atomicOr(&smask, hi & ~lo);
    }

    // ---- per-thread partial channel sum ----
    float4 ps = make_float4(0.f, 0.f, 0.f, 0.f);
    #pragma unroll
    for (int j = 0; j < CPG; ++j) {
        ps.x += v[j].x; ps.y += v[j].y; ps.z += v[j].z; ps.w += v[j].w;
    }

    __shared__ float4 part[CGROUPS][QUADS];
    part[g][q] = ps;
    __syncthreads();

    float4 tot = make_float4(0.f, 0.f, 0.f, 0.f);
    #pragma unroll
    for (int gg = 0; gg < CGROUPS; ++gg) {
        const float4 p = part[gg][q];
        tot.x += p.x; tot.y += p.y; tot.z += p.z; tot.w += p.w;
    }

    const unsigned long long m = smask;
    const int wbit = 4 * q;                    // tile-local bit of first pixel
    const float inv = 1.0f / (float)CH;
    float4 a;
    a.x = ((m >> (wbit + 0)) & 1ull) ? tot.x * inv : 0.0f;
    a.y = ((m >> (wbit + 1)) & 1ull) ? tot.y * inv : 0.0f;
    a.z = ((m >> (wbit + 2)) & 1ull) ? tot.z * inv : 0.0f;
    a.w = ((m >> (wbit + 3)) & 1ull) ? tot.w * inv : 0.0f;

    // ---- write out = x + addend straight from registers ----
    float4* __restrict__ oq = (float4*)(out + base);
    #pragma unroll
    for (int j = 0; j < CPG; ++j) {
        float4 o = v[j];
        o.x += a.x; o.y += a.y; o.z += a.z; o.w += a.w;
        oq[(size_t)j * (HWPIX / 4)] = o;
    }
}

extern "C" void kernel_launch(void* const* d_in, const int* in_sizes, int n_in,
                              void* d_out, int out_size, void* d_ws, size_t ws_size,
                              hipStream_t stream)
{
    const float*  x         = (const float*)d_in[0];
    const float4* bb4       = (const float4*)d_in[1];
    const int*    batch_idx = (const int*)d_in[2];
    float*        out       = (float*)d_out;

    const int N = in_sizes[1] / 4;             // 320 boxes
    const int B = 16;

    const int blocks = B * (HWPIX / TILE_PX);  // 4096
    k_fused<<<blocks, NTHR, 0, stream>>>(x, bb4, batch_idx, out, N);
}

// Round 8
// 106.859 us; speedup vs baseline: 1.6329x; 1.0337x over previous
//
#include <hip/hip_runtime.h>

#define CH      256
#define HH      128
#define WW      128
#define HWPIX   (HH * WW)       // 16384
#define NTHR    512
#define CPG     16              // channels per thread
#define QUADS   32              // pixel quads per row-tile (32*4 = 128 px = 1 row)

// One block = one image row (128 px) x all 256 channels.
// R4-proven elements: strided raster loop, scalar bbox loads, register-resident
// v[16] apply, plain stores. Wave-loads are 2x512B contiguous segments.
__global__ __launch_bounds__(NTHR, 4) void k_fused(
    const float* __restrict__ x,
    const float* __restrict__ bboxes,
    const int*   __restrict__ batch_idx,
    float*       __restrict__ out,
    int N)
{
    const int b = blockIdx.x >> 7;             // 128 row-tiles per image
    const int r = blockIdx.x & 127;            // row of this block
    const int q = threadIdx.x & (QUADS - 1);   // 0..31: pixel quad (cols 4q..4q+3)
    const int g = threadIdx.x >> 5;            // 0..15: channel group

    const size_t base = ((size_t)b * CH + (size_t)g * CPG) * HWPIX
                      + (size_t)r * WW + 4 * q;
    const float4* __restrict__ xq = (const float4*)(x + base);
    const size_t pstride = HWPIX / 4;

    __shared__ unsigned long long smask[2];    // [col word: 0..63 | 64..127]
    __shared__ float4 part[CPG][QUADS];        // 8 KB

    if (threadIdx.x < 2) smask[threadIdx.x] = 0ull;
    __syncthreads();

    // ---- issue all 16 loads; keep live in VGPRs ----
    float4 v[CPG];
    #pragma unroll
    for (int j = 0; j < CPG; ++j)
        v[j] = xq[(size_t)j * pstride];

    // ---- raster (R4-exact pattern), two words hand-duplicated ----
    for (int n = threadIdx.x; n < N; n += NTHR) {
        if (batch_idx[n] != b) continue;
        const float xc = bboxes[4 * n + 0];
        const float yc = bboxes[4 * n + 1];
        const float bw = bboxes[4 * n + 2];
        const float bh = bboxes[4 * n + 3];
        // match jnp.trunc(...).astype(int32) then max/min clamps exactly
        const int x1 = max(0,      (int)truncf((xc - bw * 0.5f) * (float)WW));
        const int y1 = max(0,      (int)truncf((yc - bh * 0.5f) * (float)HH));
        const int x2 = min(WW - 1, (int)truncf((xc + bw * 0.5f) * (float)WW));
        const int y2 = min(HH - 1, (int)truncf((yc + bh * 0.5f) * (float)HH));
        if (!(x2 > x1 && y2 > y1)) continue;
        if (r < y1 || r > y2) continue;
        // word 0: cols 0..63
        {
            const int a0 = x1;                 // >= 0 by clamp
            const int b0 = min(x2, 63);
            if (a0 <= b0) {
                const unsigned long long hm =
                    (b0 == 63) ? ~0ull : ((1ull << (b0 + 1)) - 1ull);
                const unsigned long long lm = (1ull << a0) - 1ull;
                atomicOr(&smask[0], hm & ~lm);
            }
        }
        // word 1: cols 64..127
        {
            const int a0 = max(x1 - 64, 0);
            const int b0 = x2 - 64;            // x2 <= 127
            if (b0 >= 0 && a0 <= b0) {
                const unsigned long long hm =
                    (b0 == 63) ? ~0ull : ((1ull << (b0 + 1)) - 1ull);
                const unsigned long long lm = (1ull << a0) - 1ull;
                atomicOr(&smask[1], hm & ~lm);
            }
        }
    }

    // ---- per-thread partial sum over its 16 channels ----
    float4 ps = make_float4(0.f, 0.f, 0.f, 0.f);
    #pragma unroll
    for (int j = 0; j < CPG; ++j) {
        ps.x += v[j].x; ps.y += v[j].y; ps.z += v[j].z; ps.w += v[j].w;
    }
    part[g][q] = ps;
    __syncthreads();                           // also covers raster completion

    float4 tot = make_float4(0.f, 0.f, 0.f, 0.f);
    #pragma unroll
    for (int gg = 0; gg < CPG; ++gg) {
        const float4 p = part[gg][q];
        tot.x += p.x; tot.y += p.y; tot.z += p.z; tot.w += p.w;
    }

    // ---- masked addend for this lane's quad ----
    const unsigned long long m = smask[q >> 4];   // col word = (4q)>>6
    const int bit0 = (4 * q) & 63;
    const float inv = 1.0f / (float)CH;
    float4 a;
    a.x = ((m >> (bit0 + 0)) & 1ull) ? tot.x * inv : 0.0f;
    a.y = ((m >> (bit0 + 1)) & 1ull) ? tot.y * inv : 0.0f;
    a.z = ((m >> (bit0 + 2)) & 1ull) ? tot.z * inv : 0.0f;
    a.w = ((m >> (bit0 + 3)) & 1ull) ? tot.w * inv : 0.0f;

    // ---- write out = x + addend straight from registers ----
    float4* __restrict__ oq = (float4*)(out + base);
    #pragma unroll
    for (int j = 0; j < CPG; ++j) {
        float4 o = v[j];
        o.x += a.x; o.y += a.y; o.z += a.z; o.w += a.w;
        oq[(size_t)j * pstride] = o;
    }
}

extern "C" void kernel_launch(void* const* d_in, const int* in_sizes, int n_in,
                              void* d_out, int out_size, void* d_ws, size_t ws_size,
                              hipStream_t stream)
{
    const float* x         = (const float*)d_in[0];
    const float* bboxes    = (const float*)d_in[1];
    const int*   batch_idx = (const int*)d_in[2];
    float*       out       = (float*)d_out;

    const int N = in_sizes[1] / 4;             // 320 boxes
    const int B = 16;

    const int blocks = B * HH;                 // 2048: one row per block
    k_fused<<<blocks, NTHR, 0, stream>>>(x, bboxes, batch_idx, out, N);
}